// Round 1
// baseline (5430.136 us; speedup 1.0000x reference)
//
#include <hip/hip_runtime.h>

// Problem constants (fixed by the reference): T=128, B=64, D=1024, H=1024
#define TT 128
#define BB 64
#define DD 1024
#define HH 1024
#define G4 4096          // 4*H
#define MM (TT*BB)       // 8192 rows of X flattened

__device__ __forceinline__ float hsig(float x) {
    x += 0.5f;
    return fminf(fmaxf(x, 0.0f), 1.0f);
}
__device__ __forceinline__ float htanh(float x) {
    return fminf(fmaxf(x, -1.0f), 1.0f);
}

// ---------------------------------------------------------------------------
// Zero-init h and c state (ws is poisoned 0xAA before every timed launch).
__global__ __launch_bounds__(256) void zero_kernel(float* p, int n) {
    int i = blockIdx.x * 256 + threadIdx.x;
    if (i < n) p[i] = 0.0f;
}

// ---------------------------------------------------------------------------
// Gx[M=8192][N=4096] = X[8192][1024] @ Wx[1024][4096] + bias
// BM=BN=64, BK=16, 256 threads, 4x4 per thread.
__global__ __launch_bounds__(256) void gx_gemm(const float* __restrict__ X,
                                               const float* __restrict__ W,
                                               const float* __restrict__ bias,
                                               float* __restrict__ C) {
    __shared__ float As[16][65];   // A-tile transposed: As[k][m], +1 pad
    __shared__ float Bs[16][64];   // B-tile: Bs[k][n]

    const int tid = threadIdx.x;
    const int tx = tid & 15;       // n-direction, 0..15
    const int ty = tid >> 4;       // m-direction, 0..15
    const int m0 = blockIdx.y * 64;
    const int n0 = blockIdx.x * 64;

    float acc[4][4] = {};

    const int ar = tid >> 2;       // 0..63 : A row
    const int aq = tid & 3;        // 0..3  : which float4 of the 16-wide row
    const int br = tid >> 4;       // 0..15 : B row
    const int bq = tid & 15;       // 0..15 : which float4 of 64-wide row

    for (int k0 = 0; k0 < DD; k0 += 16) {
        // A tile 64x16 (one float4 per thread, transposed into LDS)
        float4 a4 = *(const float4*)(X + (size_t)(m0 + ar) * DD + k0 + aq * 4);
        As[aq * 4 + 0][ar] = a4.x;
        As[aq * 4 + 1][ar] = a4.y;
        As[aq * 4 + 2][ar] = a4.z;
        As[aq * 4 + 3][ar] = a4.w;
        // B tile 16x64 (one float4 per thread)
        float4 b4 = *(const float4*)(W + (size_t)(k0 + br) * G4 + n0 + bq * 4);
        *(float4*)&Bs[br][bq * 4] = b4;
        __syncthreads();

        #pragma unroll
        for (int kk = 0; kk < 16; ++kk) {
            float av[4], bv[4];
            #pragma unroll
            for (int i = 0; i < 4; ++i) av[i] = As[kk][ty * 4 + i];
            float4 bf = *(const float4*)&Bs[kk][tx * 4];
            bv[0] = bf.x; bv[1] = bf.y; bv[2] = bf.z; bv[3] = bf.w;
            #pragma unroll
            for (int i = 0; i < 4; ++i)
                #pragma unroll
                for (int j = 0; j < 4; ++j)
                    acc[i][j] += av[i] * bv[j];
        }
        __syncthreads();
    }

    float4 bias4 = *(const float4*)(bias + n0 + tx * 4);
    #pragma unroll
    for (int i = 0; i < 4; ++i) {
        float4 o;
        o.x = acc[i][0] + bias4.x;
        o.y = acc[i][1] + bias4.y;
        o.z = acc[i][2] + bias4.z;
        o.w = acc[i][3] + bias4.w;
        *(float4*)(C + (size_t)(m0 + ty * 4 + i) * G4 + n0 + tx * 4) = o;
    }
}

// ---------------------------------------------------------------------------
// Per-step recurrent matmul partials:
//   partial[kc][b][j] = sum_{k in chunk kc} h[b][k] * Wh[k][j]
// grid = (16 j-blocks of 256 cols, 16 k-chunks of 64), block = 256.
// Each thread owns one column j and all 64 batch rows (64 accumulators);
// one Wh element is reused for 64 FMAs -> Wh traffic = 16.8 MB/step (ideal).
#define KC 16
#define KSZ 64
__global__ __launch_bounds__(256) void step_mm(const float* __restrict__ h,
                                               const float* __restrict__ Wh,
                                               float* __restrict__ partial) {
    __shared__ float hch[KSZ][BB];   // [k][b]

    const int tid = threadIdx.x;
    const int jb = blockIdx.x;       // 0..15
    const int kc = blockIdx.y;       // 0..15
    const int k0 = kc * KSZ;

    // Load h[0:64][k0:k0+64] transposed into LDS. 1024 float4s, 4 per thread.
    #pragma unroll
    for (int i = 0; i < 4; ++i) {
        int f4 = tid + 256 * i;      // 0..1023
        int b  = f4 >> 4;            // 0..63
        int q  = f4 & 15;            // 0..15
        float4 v = *(const float4*)(h + b * HH + k0 + q * 4);
        hch[q * 4 + 0][b] = v.x;
        hch[q * 4 + 1][b] = v.y;
        hch[q * 4 + 2][b] = v.z;
        hch[q * 4 + 3][b] = v.w;
    }
    __syncthreads();

    const int j = jb * 256 + tid;
    float acc[BB] = {};

    #pragma unroll 4
    for (int k = 0; k < KSZ; ++k) {
        float wh = Wh[(size_t)(k0 + k) * G4 + j];
        #pragma unroll
        for (int b4 = 0; b4 < 16; ++b4) {
            float4 h4 = *(const float4*)&hch[k][b4 * 4];
            acc[b4 * 4 + 0] += h4.x * wh;
            acc[b4 * 4 + 1] += h4.y * wh;
            acc[b4 * 4 + 2] += h4.z * wh;
            acc[b4 * 4 + 3] += h4.w * wh;
        }
    }

    float* out = partial + (size_t)(kc * BB) * G4 + j;
    #pragma unroll
    for (int b = 0; b < BB; ++b)
        out[(size_t)b * G4] = acc[b];
}

// ---------------------------------------------------------------------------
// Cell update: gates = Gx[t] + sum_kc partial; apply hard-LSTM; write c,h,out.
__global__ __launch_bounds__(256) void cell_kernel(const float* __restrict__ Gxt,
                                                   const float* __restrict__ partial,
                                                   float* __restrict__ c,
                                                   float* __restrict__ h,
                                                   float* __restrict__ out_t) {
    const int idx = blockIdx.x * 256 + threadIdx.x;  // 0..65535
    const int b = idx >> 10;
    const int k = idx & 1023;

    const float* gr = Gxt + (size_t)b * G4;
    float gi = gr[k];
    float gf = gr[HH + k];
    float gg = gr[2 * HH + k];
    float go = gr[3 * HH + k];

    #pragma unroll
    for (int kc = 0; kc < KC; ++kc) {
        const float* p = partial + (size_t)(kc * BB + b) * G4;
        gi += p[k];
        gf += p[HH + k];
        gg += p[2 * HH + k];
        go += p[3 * HH + k];
    }

    float i = hsig(gi);
    float f = hsig(gf);
    float g = htanh(gg);
    float o = hsig(go);

    float cn = f * c[idx] + i * g;
    c[idx] = cn;
    float hn = o * htanh(cn);
    h[idx] = hn;
    out_t[idx] = hn;
}

// ---------------------------------------------------------------------------
extern "C" void kernel_launch(void* const* d_in, const int* in_sizes, int n_in,
                              void* d_out, int out_size, void* d_ws, size_t ws_size,
                              hipStream_t stream) {
    const float* x  = (const float*)d_in[0];   // [T,B,D]
    const float* Wx = (const float*)d_in[1];   // [D,4H]
    const float* Wh = (const float*)d_in[2];   // [H,4H]
    const float* bs = (const float*)d_in[3];   // [4H]
    float* out = (float*)d_out;                // [T,B,H]

    // Workspace layout (floats):
    //   Gx      : MM*G4        = 33,554,432
    //   partial : KC*BB*G4     =  4,194,304
    //   hbuf    : BB*HH        =     65,536
    //   cbuf    : BB*HH        =     65,536
    float* Gx      = (float*)d_ws;
    float* partial = Gx + (size_t)MM * G4;
    float* hbuf    = partial + (size_t)KC * BB * G4;
    float* cbuf    = hbuf + BB * HH;

    // zero h0, c0 (ws is poisoned before every call)
    zero_kernel<<<dim3((2 * BB * HH + 255) / 256), dim3(256), 0, stream>>>(hbuf, 2 * BB * HH);

    // Gx = X @ Wx + b  (all timesteps at once)
    gx_gemm<<<dim3(G4 / 64, MM / 64), dim3(256), 0, stream>>>(x, Wx, bs, Gx);

    for (int t = 0; t < TT; ++t) {
        step_mm<<<dim3(16, KC), dim3(256), 0, stream>>>(hbuf, Wh, partial);
        cell_kernel<<<dim3(BB * HH / 256), dim3(256), 0, stream>>>(
            Gx + (size_t)t * BB * G4, partial, cbuf, hbuf, out + (size_t)t * BB * HH);
    }
}